// Round 1
// baseline (131.704 us; speedup 1.0000x reference)
//
#include <hip/hip_runtime.h>

// LSSM: x_t = x_{t-1} A^T + u_t B^T ; y_t = x_t C^T + u_t D^T ; x_0 = 0
// B=16, SEQ=8192, all dims 128.
//
// Strategy: chunked parallel scan. 256 chunks of length 32.
//  k_chunk: per-chunk local scan (zero entry) -> E[c]; identity wgs -> P = (A^T)^32
//  k_group: groups of 16 chunks -> E2[g]; identity wgs -> Pg = P^16
//  k_top:   1 wg scans 16 groups -> group entry states S2[g]
//  k_fix:   per group, re-scan 16 chunk transitions -> chunk entry states S[c]
//  k_main:  per-chunk re-scan from true entry state, fused y = x C^T + u D^T
// All matmuls are [16,128]x[128,128] via mfma_f32_16x16x32_bf16 with hi/lo
// split (3 products per matrix pair) => ~2^-16 relative error per step.
// State crosses waves through XOR-swizzled LDS (row-major [16][128] bf16,
// element j ^= (row&7)<<3) to avoid the 16-way bank conflict on b128 reads.

#define SEQ 8192
#define BS  16
#define DD  128
#define CL  32           // chunk length
#define NC  256          // SEQ / CL
#define GRP 16           // chunks per group
#define NG  16           // NC / GRP

typedef __bf16 bf16t;
typedef __bf16 bf16x8 __attribute__((ext_vector_type(8)));
typedef __bf16 bf16x4 __attribute__((ext_vector_type(4)));
typedef float  f32x4  __attribute__((ext_vector_type(4)));

#define MFMA(a,b,c) __builtin_amdgcn_mfma_f32_16x16x32_bf16(a,b,c,0,0,0)

__device__ __forceinline__ int swz(int b, int j) { return j ^ ((b & 7) << 3); }

struct Frag { bf16x8 h[4]; bf16x8 l[4]; };

// B-operand frags of M where M[k][n] = src[n][k]  (src row-major [128][128])
// lane&15 -> n (within tile w), (lane>>4, e) -> k   (contiguous in e: fast)
__device__ __forceinline__ void load_frag_T(const float* __restrict__ src, int lane, int w, Frag& f) {
    int n  = (w << 4) + (lane & 15);
    int kb = ((lane >> 4) & 3) << 3;
#pragma unroll
    for (int q = 0; q < 4; q++) {
        const float* p = src + n * DD + (q << 5) + kb;
#pragma unroll
        for (int e = 0; e < 8; e++) {
            float v = p[e];
            bf16t hh = (bf16t)v;
            f.h[q][e] = hh;
            f.l[q][e] = (bf16t)(v - (float)hh);
        }
    }
}

// B-operand frags of M where M[k][n] = src[k][n]  (no transpose; strided gather)
__device__ __forceinline__ void load_frag_N(const float* __restrict__ src, int lane, int w, Frag& f) {
    int n  = (w << 4) + (lane & 15);
    int kb = ((lane >> 4) & 3) << 3;
#pragma unroll
    for (int q = 0; q < 4; q++) {
#pragma unroll
        for (int e = 0; e < 8; e++) {
            float v = src[((q << 5) + kb + e) * DD + n];
            bf16t hh = (bf16t)v;
            f.h[q][e] = hh;
            f.l[q][e] = (bf16t)(v - (float)hh);
        }
    }
}

// A-operand frag from swizzled LDS state [16][128] bf16: lane&15 -> row b
__device__ __forceinline__ bf16x8 afrag(const bf16t* __restrict__ X, int lane, int q) {
    int b  = lane & 15;
    int j0 = (q << 5) + (((lane >> 4) & 3) << 3);
    return *(const bf16x8*)(X + b * DD + swz(b, j0));
}

// D-frag (f32x4) -> hi/lo bf16 swizzled LDS.  D layout: col=lane&15, row=(lane>>4)*4+r
__device__ __forceinline__ void put_state(bf16t* __restrict__ H, bf16t* __restrict__ L,
                                          int lane, int w, f32x4 acc) {
    int n = (w << 4) + (lane & 15);
#pragma unroll
    for (int r = 0; r < 4; r++) {
        int b = (((lane >> 4) & 3) << 2) + r;
        float v = acc[r];
        bf16t hh = (bf16t)v;
        H[b * DD + swz(b, n)] = hh;
        L[b * DD + swz(b, n)] = (bf16t)(v - (float)hh);
    }
}

// cooperative: 16x128 fp32 block (row stride rs) -> hi/lo swizzled LDS (512 thr)
__device__ __forceinline__ void stage_rows(const float* __restrict__ src, long rs,
                                           bf16t* __restrict__ H, bf16t* __restrict__ L, int tid) {
    int b  = tid >> 5;
    int j0 = (tid & 31) << 2;
    float4 v = *(const float4*)(src + (long)b * rs + j0);
    float vv[4] = { v.x, v.y, v.z, v.w };
    bf16x4 h, l;
#pragma unroll
    for (int e = 0; e < 4; e++) {
        bf16t hh = (bf16t)vv[e];
        h[e] = hh;
        l[e] = (bf16t)(vv[e] - (float)hh);
    }
    *(bf16x4*)(H + b * DD + swz(b, j0)) = h;
    *(bf16x4*)(L + b * DD + swz(b, j0)) = l;
}

__device__ __forceinline__ f32x4 load_accfrag(const float* __restrict__ src, int lane, int w) {
    int n = (w << 4) + (lane & 15);
    f32x4 a;
#pragma unroll
    for (int r = 0; r < 4; r++) {
        int b = (((lane >> 4) & 3) << 2) + r;
        a[r] = src[b * DD + n];
    }
    return a;
}

__device__ __forceinline__ void store_accfrag(float* __restrict__ dst, int lane, int w,
                                              f32x4 a, long rs) {
    int n = (w << 4) + (lane & 15);
#pragma unroll
    for (int r = 0; r < 4; r++) {
        int b = (((lane >> 4) & 3) << 2) + r;
        dst[(long)b * rs + n] = a[r];
    }
}

// ---------------- k_chunk: local chunk scans + P = (A^T)^CL ----------------
__global__ __launch_bounds__(512) void k_chunk(const float* __restrict__ u,
                                               const float* __restrict__ A,
                                               const float* __restrict__ B,
                                               float* __restrict__ E,
                                               float* __restrict__ P) {
    __shared__ __align__(16) bf16t Xh[2][BS * DD], Xl[2][BS * DD];
    __shared__ __align__(16) bf16t Uh[2][BS * DD], Ul[2][BS * DD];
    int tid = threadIdx.x, lane = tid & 63, w = tid >> 6;
    bool ident = blockIdx.x >= NC;
    int g2 = blockIdx.x - NC;

    Frag fA, fB;
    load_frag_T(A, lane, w, fA);
    if (!ident) load_frag_T(B, lane, w, fB);

    // init state: zero, or identity rows R = g2*16 + b (swizzle-aware, race-free)
    for (int i = tid; i < BS * DD; i += 512) {
        int b = i >> 7, j = swz(b, i & 127);
        float v = (ident && j == g2 * 16 + b) ? 1.f : 0.f;
        Xh[0][i] = (bf16t)v;
        Xl[0][i] = (bf16t)0.f;
    }
    int c = blockIdx.x;
    const float* ubase = u + (long)c * CL * DD;   // + b*SEQ*DD + i*DD + j
    int b_ = tid >> 5, j0_ = (tid & 31) << 2;
    if (!ident) stage_rows(ubase, (long)SEQ * DD, Uh[0], Ul[0], tid);
    __syncthreads();

    int p = 0;
    f32x4 acc = {0.f, 0.f, 0.f, 0.f};
    for (int i = 0; i < CL; i++) {
        float4 un = {0.f, 0.f, 0.f, 0.f};
        if (!ident && i + 1 < CL)
            un = *(const float4*)(ubase + (long)b_ * SEQ * DD + (i + 1) * DD + j0_);
        f32x4 ax = {0.f,0.f,0.f,0.f}, ax2 = {0.f,0.f,0.f,0.f};
#pragma unroll
        for (int q = 0; q < 4; q++) {
            bf16x8 xh = afrag(Xh[p], lane, q), xl = afrag(Xl[p], lane, q);
            ax  = MFMA(xh, fA.h[q], ax);
            ax2 = MFMA(xl, fA.h[q], ax2);
            ax  = MFMA(xh, fA.l[q], ax);
            if (!ident) {
                bf16x8 uh = afrag(Uh[i & 1], lane, q), ul = afrag(Ul[i & 1], lane, q);
                ax2 = MFMA(uh, fB.h[q], ax2);
                ax  = MFMA(ul, fB.h[q], ax);
                ax2 = MFMA(uh, fB.l[q], ax2);
            }
        }
        acc = ax + ax2;
        if (i + 1 < CL) {
            put_state(Xh[p ^ 1], Xl[p ^ 1], lane, w, acc);
            if (!ident) {
                float vv[4] = { un.x, un.y, un.z, un.w };
                bf16x4 h, l;
#pragma unroll
                for (int e = 0; e < 4; e++) {
                    bf16t hh = (bf16t)vv[e];
                    h[e] = hh;
                    l[e] = (bf16t)(vv[e] - (float)hh);
                }
                *(bf16x4*)(Uh[(i + 1) & 1] + b_ * DD + swz(b_, j0_)) = h;
                *(bf16x4*)(Ul[(i + 1) & 1] + b_ * DD + swz(b_, j0_)) = l;
            }
            __syncthreads();
            p ^= 1;
        }
    }
    if (!ident) store_accfrag(E + (long)c * BS * DD, lane, w, acc, DD);
    else        store_accfrag(P + (long)g2 * 16 * DD, lane, w, acc, DD);
}

// ---------------- k_group: E2[g] over 16 chunks + Pg = P^16 ----------------
__global__ __launch_bounds__(512) void k_group(const float* __restrict__ E,
                                               const float* __restrict__ P,
                                               float* __restrict__ E2,
                                               float* __restrict__ Pg) {
    __shared__ __align__(16) bf16t Xh[2][BS * DD], Xl[2][BS * DD];
    int tid = threadIdx.x, lane = tid & 63, w = tid >> 6;
    bool ident = blockIdx.x >= NG;
    int g2 = blockIdx.x - NG;
    Frag fP;
    load_frag_N(P, lane, w, fP);
    for (int i = tid; i < BS * DD; i += 512) {
        int b = i >> 7, j = swz(b, i & 127);
        float v = (ident && j == g2 * 16 + b) ? 1.f : 0.f;
        Xh[0][i] = (bf16t)v;
        Xl[0][i] = (bf16t)0.f;
    }
    __syncthreads();
    int p = 0, g = blockIdx.x;
    f32x4 acc = {0.f, 0.f, 0.f, 0.f};
    for (int r = 0; r < GRP; r++) {
        f32x4 a1 = {0.f,0.f,0.f,0.f}, a2 = {0.f,0.f,0.f,0.f};
        if (!ident) a1 = load_accfrag(E + (long)(g * GRP + r) * BS * DD, lane, w);
#pragma unroll
        for (int q = 0; q < 4; q++) {
            bf16x8 xh = afrag(Xh[p], lane, q), xl = afrag(Xl[p], lane, q);
            a1 = MFMA(xh, fP.h[q], a1);
            a2 = MFMA(xl, fP.h[q], a2);
            a1 = MFMA(xh, fP.l[q], a1);
        }
        acc = a1 + a2;
        if (r + 1 < GRP) {
            put_state(Xh[p ^ 1], Xl[p ^ 1], lane, w, acc);
            __syncthreads();
            p ^= 1;
        }
    }
    if (!ident) store_accfrag(E2 + (long)g * BS * DD, lane, w, acc, DD);
    else        store_accfrag(Pg + (long)g2 * 16 * DD, lane, w, acc, DD);
}

// ---------------- k_top: 1 wg, group entry states S2[g] ----------------
__global__ __launch_bounds__(512) void k_top(const float* __restrict__ E2,
                                             const float* __restrict__ Pg,
                                             float* __restrict__ S2) {
    __shared__ __align__(16) bf16t Xh[2][BS * DD], Xl[2][BS * DD];
    int tid = threadIdx.x, lane = tid & 63, w = tid >> 6;
    Frag fP;
    load_frag_N(Pg, lane, w, fP);
    for (int i = tid; i < BS * DD; i += 512) {
        Xh[0][i] = (bf16t)0.f;
        Xl[0][i] = (bf16t)0.f;
    }
    __syncthreads();
    int p = 0;
    f32x4 T = {0.f, 0.f, 0.f, 0.f};
    for (int g = 0; g < NG; g++) {
        store_accfrag(S2 + (long)g * BS * DD, lane, w, T, DD);   // entry state of group g
        f32x4 a1 = load_accfrag(E2 + (long)g * BS * DD, lane, w), a2 = {0.f,0.f,0.f,0.f};
#pragma unroll
        for (int q = 0; q < 4; q++) {
            bf16x8 xh = afrag(Xh[p], lane, q), xl = afrag(Xl[p], lane, q);
            a1 = MFMA(xh, fP.h[q], a1);
            a2 = MFMA(xl, fP.h[q], a2);
            a1 = MFMA(xh, fP.l[q], a1);
        }
        T = a1 + a2;
        if (g + 1 < NG) {
            put_state(Xh[p ^ 1], Xl[p ^ 1], lane, w, T);
            __syncthreads();
            p ^= 1;
        }
    }
}

// ---------------- k_fix: chunk entry states S[c] ----------------
__global__ __launch_bounds__(512) void k_fix(const float* __restrict__ E,
                                             const float* __restrict__ P,
                                             const float* __restrict__ S2,
                                             float* __restrict__ S) {
    __shared__ __align__(16) bf16t Xh[2][BS * DD], Xl[2][BS * DD];
    int tid = threadIdx.x, lane = tid & 63, w = tid >> 6;
    int g = blockIdx.x;
    Frag fP;
    load_frag_N(P, lane, w, fP);
    stage_rows(S2 + (long)g * BS * DD, DD, Xh[0], Xl[0], tid);
    f32x4 T = load_accfrag(S2 + (long)g * BS * DD, lane, w);
    __syncthreads();
    int p = 0;
    for (int r = 0; r < GRP; r++) {
        int c = g * GRP + r;
        store_accfrag(S + (long)c * BS * DD, lane, w, T, DD);    // entry state of chunk c
        if (r + 1 == GRP) break;
        f32x4 a1 = load_accfrag(E + (long)c * BS * DD, lane, w), a2 = {0.f,0.f,0.f,0.f};
#pragma unroll
        for (int q = 0; q < 4; q++) {
            bf16x8 xh = afrag(Xh[p], lane, q), xl = afrag(Xl[p], lane, q);
            a1 = MFMA(xh, fP.h[q], a1);
            a2 = MFMA(xl, fP.h[q], a2);
            a1 = MFMA(xh, fP.l[q], a1);
        }
        T = a1 + a2;
        put_state(Xh[p ^ 1], Xl[p ^ 1], lane, w, T);
        __syncthreads();
        p ^= 1;
    }
}

// ---------------- k_main: final scan + fused output ----------------
__global__ __launch_bounds__(512) void k_main(const float* __restrict__ u,
                                              const float* __restrict__ A,
                                              const float* __restrict__ B,
                                              const float* __restrict__ C,
                                              const float* __restrict__ D,
                                              const float* __restrict__ S,
                                              float* __restrict__ out) {
    __shared__ __align__(16) bf16t Xh[2][BS * DD], Xl[2][BS * DD];
    __shared__ __align__(16) bf16t Uh[2][BS * DD], Ul[2][BS * DD];
    int tid = threadIdx.x, lane = tid & 63, w = tid >> 6;
    Frag fA, fB, fC, fD;
    load_frag_T(A, lane, w, fA);
    load_frag_T(B, lane, w, fB);
    load_frag_T(C, lane, w, fC);
    load_frag_T(D, lane, w, fD);
    int c = blockIdx.x;
    const float* ubase = u + (long)c * CL * DD;
    int b_ = tid >> 5, j0_ = (tid & 31) << 2;
    stage_rows(S + (long)c * BS * DD, DD, Xh[0], Xl[0], tid);
    stage_rows(ubase, (long)SEQ * DD, Uh[0], Ul[0], tid);
    __syncthreads();
    int p = 0;
    for (int i = 0; i < CL; i++) {
        float4 un = {0.f, 0.f, 0.f, 0.f};
        if (i + 1 < CL)
            un = *(const float4*)(ubase + (long)b_ * SEQ * DD + (i + 1) * DD + j0_);
        f32x4 ax = {0.f,0.f,0.f,0.f}, ax2 = {0.f,0.f,0.f,0.f};
        f32x4 ay = {0.f,0.f,0.f,0.f}, ay2 = {0.f,0.f,0.f,0.f};
#pragma unroll
        for (int q = 0; q < 4; q++) {
            bf16x8 xh = afrag(Xh[p], lane, q), xl = afrag(Xl[p], lane, q);
            bf16x8 uh = afrag(Uh[i & 1], lane, q), ul = afrag(Ul[i & 1], lane, q);
            ax  = MFMA(xh, fA.h[q], ax);
            ax2 = MFMA(xl, fA.h[q], ax2);
            ax  = MFMA(xh, fA.l[q], ax);
            ax2 = MFMA(uh, fB.h[q], ax2);
            ax  = MFMA(ul, fB.h[q], ax);
            ax2 = MFMA(uh, fB.l[q], ax2);
            ay  = MFMA(uh, fD.h[q], ay);
            ay2 = MFMA(ul, fD.h[q], ay2);
            ay  = MFMA(uh, fD.l[q], ay);
        }
        f32x4 xnew = ax + ax2;
        put_state(Xh[p ^ 1], Xl[p ^ 1], lane, w, xnew);   // x_t for C-product + next step
        if (i + 1 < CL) {
            float vv[4] = { un.x, un.y, un.z, un.w };
            bf16x4 h, l;
#pragma unroll
            for (int e = 0; e < 4; e++) {
                bf16t hh = (bf16t)vv[e];
                h[e] = hh;
                l[e] = (bf16t)(vv[e] - (float)hh);
            }
            *(bf16x4*)(Uh[(i + 1) & 1] + b_ * DD + swz(b_, j0_)) = h;
            *(bf16x4*)(Ul[(i + 1) & 1] + b_ * DD + swz(b_, j0_)) = l;
        }
        __syncthreads();
#pragma unroll
        for (int q = 0; q < 4; q++) {
            bf16x8 nh = afrag(Xh[p ^ 1], lane, q), nl = afrag(Xl[p ^ 1], lane, q);
            ay  = MFMA(nh, fC.h[q], ay);
            ay2 = MFMA(nl, fC.h[q], ay2);
            ay  = MFMA(nh, fC.l[q], ay);
        }
        f32x4 y = ay + ay2;
        store_accfrag(out + ((long)c * CL + i) * DD, lane, w, y, (long)SEQ * DD);
        p ^= 1;
    }
}

extern "C" void kernel_launch(void* const* d_in, const int* in_sizes, int n_in,
                              void* d_out, int out_size, void* d_ws, size_t ws_size,
                              hipStream_t stream) {
    (void)in_sizes; (void)n_in; (void)out_size; (void)ws_size;
    const float* u = (const float*)d_in[0];
    const float* A = (const float*)d_in[1];
    const float* B = (const float*)d_in[2];
    const float* C = (const float*)d_in[3];
    const float* D = (const float*)d_in[4];
    float* out = (float*)d_out;
    float* ws  = (float*)d_ws;
    // ws layout (floats): P 16384 | Pg 16384 | E 524288 | E2 32768 | S2 32768 | S 524288
    // total ~4.6 MB
    float* P  = ws;
    float* Pg = ws + 16384;
    float* E  = ws + 32768;
    float* E2 = ws + 32768 + 524288;
    float* S2 = E2 + 32768;
    float* S  = S2 + 32768;
    dim3 blk(512);
    k_chunk<<<NC + 8, blk, 0, stream>>>(u, A, B, E, P);
    k_group<<<NG + 8, blk, 0, stream>>>(E, P, E2, Pg);
    k_top  <<<1,      blk, 0, stream>>>(E2, Pg, S2);
    k_fix  <<<NG,     blk, 0, stream>>>(E, P, S2, S);
    k_main <<<NC,     blk, 0, stream>>>(u, A, B, C, D, S, out);
}